// Round 15
// baseline (87.584 us; speedup 1.0000x reference)
//
#include <hip/hip_runtime.h>
#include <stdint.h>

typedef float f32x4 __attribute__((ext_vector_type(4)));
typedef short short8 __attribute__((ext_vector_type(8)));
typedef short short4v __attribute__((ext_vector_type(4)));

#define N_SPATIAL 65536   // 256*256

__device__ __forceinline__ float b2f(uint16_t u) {
  union { uint32_t u; float f; } v; v.u = ((uint32_t)u) << 16; return v.f;
}
__device__ __forceinline__ uint16_t f2b(float f) {
  union { float f; uint32_t u; } v; v.f = f;
  uint32_t r = (v.u + 0x7FFFu + ((v.u >> 16) & 1u)) >> 16;
  return (uint16_t)r;
}

// async 16B global -> LDS (direct).  LDS dest wave-uniform base + lane*16.
__device__ __forceinline__ void async16(const void* g, void* l) {
  __builtin_amdgcn_global_load_lds(
      (__attribute__((address_space(1))) void*)g,
      (__attribute__((address_space(3))) void*)l, 16, 0, 0);
}

// ---------------------------------------------------------------------------
// K1 (R10-proven): transpose x (c,n) fp32 -> xT (n,c) bf16 + GN partial stats.
// grid 1024 (64-n tiles), block 256.
__global__ __launch_bounds__(256) void k1_transpose_stats(
    const float* __restrict__ x, uint16_t* __restrict__ xT, float* __restrict__ gnp) {
  __shared__ uint16_t xs[64][264];   // [n][c] padded stride 264
  const int t = threadIdx.x;
  const int n0 = blockIdx.x * 64;
  const int c_l = (t >> 2) & 15;
  const int nq  = (t & 3) + 4 * (t >> 6);
  for (int p = 0; p < 16; ++p) {
    int c = 16 * p + c_l;
    float4 v = *(const float4*)(x + (size_t)c * N_SPATIAL + n0 + nq * 4);
    int nn = nq * 4;
    xs[nn + 0][c] = f2b(v.x); xs[nn + 1][c] = f2b(v.y);
    xs[nn + 2][c] = f2b(v.z); xs[nn + 3][c] = f2b(v.w);
  }
  __syncthreads();
  {
    int g = t >> 3; int c = g * 8 + (t & 7);
    float s = 0.f, ss = 0.f;
    for (int n = 0; n < 64; ++n) { float f = b2f(xs[n][c]); s += f; ss += f * f; }
    s  += __shfl_xor(s, 1, 64);  ss += __shfl_xor(ss, 1, 64);
    s  += __shfl_xor(s, 2, 64);  ss += __shfl_xor(ss, 2, 64);
    s  += __shfl_xor(s, 4, 64);  ss += __shfl_xor(ss, 4, 64);
    if ((t & 7) == 0) {
      gnp[((size_t)blockIdx.x * 32 + g) * 2 + 0] = s;
      gnp[((size_t)blockIdx.x * 32 + g) * 2 + 1] = ss;
    }
  }
  for (int p = 0; p < 8; ++p) {
    int j = t + 256 * p; int n = j >> 5; int c16 = j & 31;
    f32x4 val = *(const f32x4*)((const char*)&xs[0][0] + n * 528 + c16 * 16);
    *(f32x4*)((char*)xT + ((size_t)(n0 + n)) * 512 + c16 * 16) = val;
  }
}

// ---------------------------------------------------------------------------
// K2s: reduce stats partials -> per-channel a,b.  grid 32, block 256.
__global__ __launch_bounds__(256) void k2_stats_final(
    const float* __restrict__ gnp, const float* __restrict__ gnw,
    const float* __restrict__ gnb, float* __restrict__ ab) {
  __shared__ float red[4][2];
  const int g = blockIdx.x; const int t = threadIdx.x;
  float s = 0.f, ss = 0.f;
  for (int c = t; c < 1024; c += 256) {
    s  += gnp[((size_t)c * 32 + g) * 2 + 0];
    ss += gnp[((size_t)c * 32 + g) * 2 + 1];
  }
  for (int m = 32; m >= 1; m >>= 1) { s += __shfl_xor(s, m, 64); ss += __shfl_xor(ss, m, 64); }
  if ((t & 63) == 0) { red[t >> 6][0] = s; red[t >> 6][1] = ss; }
  __syncthreads();
  if (t == 0) {
    float S  = red[0][0] + red[1][0] + red[2][0] + red[3][0];
    float SS = red[0][1] + red[1][1] + red[2][1] + red[3][1];
    const float invN = 1.0f / 524288.0f;
    float mean = S * invN;
    float var  = SS * invN - mean * mean;
    float rs   = rsqrtf(var + 1e-5f);
    for (int i = 0; i < 8; ++i) {
      int c = g * 8 + i;
      float aa = gnw[c] * rs;
      ab[c] = aa;
      ab[256 + c] = gnb[c] - mean * aa;
    }
  }
}

// ---------------------------------------------------------------------------
// K2w: fold norm into qkv weights.  grid 384, block 64.
__global__ __launch_bounds__(64) void k2b_fold_w(
    const float* __restrict__ qw, const float* __restrict__ qb,
    const float* __restrict__ ab, uint16_t* __restrict__ wp, float* __restrict__ biasp) {
  const int o = blockIdx.x; const int l = threadIdx.x;
  float4 w  = *(const float4*)(qw + (size_t)o * 256 + l * 4);
  float4 av = *(const float4*)(ab + l * 4);
  float4 bv = *(const float4*)(ab + 256 + l * 4);
  short4v pk;
  pk[0] = (short)f2b(w.x * av.x); pk[1] = (short)f2b(w.y * av.y);
  pk[2] = (short)f2b(w.z * av.z); pk[3] = (short)f2b(w.w * av.w);
  *(short4v*)(wp + (size_t)o * 256 + l * 4) = pk;
  float part = w.x * bv.x + w.y * bv.y + w.z * bv.z + w.w * bv.w;
  for (int m = 32; m >= 1; m >>= 1) part += __shfl_xor(part, m, 64);
  if (l == 0) biasp[o] = qb[o] + part;
}

// ---------------------------------------------------------------------------
// K3kv v5: BN=128 per block (8 waves), grid 512.  Same 11 barriers/block now
// cover 2x MFMA work; wp L2 re-staging halves.  LDS 64KB, 2 blocks/CU
// (16 waves/CU = same occupancy as BN=64 config).
// GEMM: wave (wr=wid>>1 -> 64 kv-rows, wc=wid&1 -> 64-px half).
// Epilogue: k-waves (wid<4) exp -> ekbuf[128][256B]; v-waves -> vbuf.
// Context: wave (h=wid&3, ph=wid>>2 px-half); part[512][2][4224] flat ==
// [1024][4224] -> k6/kM byte-identical.
__global__ __launch_bounds__(512, 2) void k3_kv(
    const uint16_t* __restrict__ xT, const uint16_t* __restrict__ wp,
    const float* __restrict__ biasp, uint16_t* __restrict__ part) {
  __shared__ __align__(16) char smem[65536]; // stage A[0,32K) B[32K,48K); ek[0,32K) v[32K,64K)
  const int t = threadIdx.x;
  const int l = t & 63, wid = t >> 6;
  const int lrow = l & 15, lk = l >> 4;
  const int wr = wid >> 1, wc = wid & 1;

  const int n0 = blockIdx.x * 128;
  f32x4 acc[4][4] = {};
  for (int ks = 0; ks < 4; ++ks) {
    const int k0 = ks * 64;
    __syncthreads();
    #pragma unroll
    for (int it = 0; it < 4; ++it) {
      int s = it * 512 + t;                 // 0..2047: A rows 0..255, 8 chunks
      int row = s >> 3, c = s & 7;
      const char* gsrc = (const char*)wp + (size_t)(128 + row) * 512 + k0 * 2 + ((c ^ (row & 7)) << 4);
      async16(gsrc, smem + (s & ~63) * 16);
    }
    #pragma unroll
    for (int it = 0; it < 2; ++it) {
      int s = it * 512 + t;                 // 0..1023: B rows 0..127, 8 chunks
      int row = s >> 3, c = s & 7;
      const char* gsrc = (const char*)xT + (size_t)(n0 + row) * 512 + k0 * 2 + ((c ^ (row & 7)) << 4);
      async16(gsrc, smem + 32768 + (s & ~63) * 16);
    }
    __syncthreads();
    #pragma unroll
    for (int kk = 0; kk < 2; ++kk) {
      short8 a[4], b[4];
      #pragma unroll
      for (int m = 0; m < 4; ++m) {
        int row = wr * 64 + m * 16 + lrow;
        a[m] = *(const short8*)(&smem[row * 128 + (((kk * 4 + lk) ^ (row & 7)) << 4)]);
      }
      #pragma unroll
      for (int n = 0; n < 4; ++n) {
        int row = wc * 64 + n * 16 + lrow;
        b[n] = *(const short8*)(&smem[32768 + row * 128 + (((kk * 4 + lk) ^ (row & 7)) << 4)]);
      }
      #pragma unroll
      for (int m = 0; m < 4; ++m)
        #pragma unroll
        for (int n = 0; n < 4; ++n)
          acc[m][n] = __builtin_amdgcn_mfma_f32_16x16x32_bf16(a[m], b[n], acc[m][n], 0, 0, 0);
    }
  }
  __syncthreads();

  float denp[16];
  #pragma unroll
  for (int i = 0; i < 16; ++i) denp[i] = 0.f;
  {
    const bool isk = wr < 2;
    const int base = isk ? 0 : 32768;
    #pragma unroll
    for (int m = 0; m < 4; ++m) {
      float bb[4];
      #pragma unroll
      for (int j = 0; j < 4; ++j) bb[j] = biasp[128 + wr * 64 + m * 16 + lk * 4 + j];
      #pragma unroll
      for (int n = 0; n < 4; ++n) {
        int col = wc * 64 + n * 16 + lrow;       // px 0..127
        int coff = col >> 3, cbyte = (col & 7) * 2;
        #pragma unroll
        for (int j = 0; j < 4; ++j) {
          int rloc = (wr & 1) * 64 + m * 16 + lk * 4 + j;   // row within 128
          float val = acc[m][n][j] + bb[j];
          if (isk) { val = __expf(val); denp[m * 4 + j] += val; }
          *(uint16_t*)(&smem[base + rloc * 256 + ((coff ^ (rloc & 7)) << 4) + cbyte]) = f2b(val);
        }
      }
    }
  }
  __syncthreads();

  f32x4 cacc[2][2] = {};
  {
    const int h = wid & 3, ph = wid >> 2;        // head, px-half
    #pragma unroll
    for (int kw = 0; kw < 2; ++kw) {
      short8 ae[2], be[2];
      #pragma unroll
      for (int mf = 0; mf < 2; ++mf) {
        int row = h * 32 + mf * 16 + lrow;
        int coff = ph * 8 + kw * 4 + lk;
        ae[mf] = *(const short8*)(&smem[row * 256 + ((coff ^ (row & 7)) << 4)]);
      }
      #pragma unroll
      for (int nf = 0; nf < 2; ++nf) {
        int row = h * 32 + nf * 16 + lrow;
        int coff = ph * 8 + kw * 4 + lk;
        be[nf] = *(const short8*)(&smem[32768 + row * 256 + ((coff ^ (row & 7)) << 4)]);
      }
      #pragma unroll
      for (int mf = 0; mf < 2; ++mf)
        #pragma unroll
        for (int nf = 0; nf < 2; ++nf)
          cacc[mf][nf] = __builtin_amdgcn_mfma_f32_16x16x32_bf16(ae[mf], be[nf], cacc[mf][nf], 0, 0, 0);
    }
  }
  // part flat: [block][ph*4224 + h*1056 + ...] == [1024 chunks][4224]
  uint16_t* pp = part + (size_t)blockIdx.x * 8448;
  {
    const int h = wid & 3, ph = wid >> 2;
    uint16_t* phd = pp + (size_t)ph * 4224 + h * 1056;
    #pragma unroll
    for (int mf = 0; mf < 2; ++mf)
      #pragma unroll
      for (int nf = 0; nf < 2; ++nf)
        #pragma unroll
        for (int j = 0; j < 4; ++j) {
          int d = mf * 16 + lk * 4 + j, e = nf * 16 + lrow;
          __builtin_nontemporal_store(f2b(cacc[mf][nf][j]), &phd[d * 32 + e]);
        }
  }
  if (wr < 2) {
    #pragma unroll
    for (int i = 0; i < 16; ++i) {
      denp[i] += __shfl_xor(denp[i], 1, 64);
      denp[i] += __shfl_xor(denp[i], 2, 64);
      denp[i] += __shfl_xor(denp[i], 4, 64);
      denp[i] += __shfl_xor(denp[i], 8, 64);
    }
    if (lrow == 0) {
      #pragma unroll
      for (int m = 0; m < 4; ++m)
        #pragma unroll
        for (int j = 0; j < 4; ++j) {
          int r = wr * 64 + m * 16 + lk * 4 + j;   // 0..127 k-row; h = r>>5
          __builtin_nontemporal_store(
              f2b(denp[m * 4 + j]),
              &pp[(size_t)wc * 4224 + (r >> 5) * 1056 + 1024 + (r & 31)]);
        }
    }
  }
}

// ---------------------------------------------------------------------------
// K6 (R10-proven 8-way): reduce bf16 partials over 1024 logical chunks.
// grid 136 = 17 x 8.  part2[8][4224] fp32.
__global__ __launch_bounds__(256) void k6_reduce(
    const uint16_t* __restrict__ part, float* __restrict__ part2) {
  const int bx = blockIdx.x;
  const int idb = bx % 17, cg = bx / 17;
  const int id = idb * 256 + threadIdx.x;
  if (id >= 4224) return;
  const uint16_t* p = part + (size_t)cg * 128 * 4224 + id;
  float s0 = 0.f, s1 = 0.f, s2 = 0.f, s3 = 0.f;
  for (int c = 0; c < 128; c += 4) {
    s0 += b2f(p[(size_t)(c + 0) * 4224]);
    s1 += b2f(p[(size_t)(c + 1) * 4224]);
    s2 += b2f(p[(size_t)(c + 2) * 4224]);
    s3 += b2f(p[(size_t)(c + 3) * 4224]);
  }
  part2[cg * 4224 + id] = (s0 + s1) + (s2 + s3);
}

// ---------------------------------------------------------------------------
// KM (R10-proven): merged M-fold + M2-fold (sums the 8 part2 chunks on load).
// grid 256, block 256.
__global__ __launch_bounds__(256) void kM_fold(
    const float* __restrict__ ow, const float* __restrict__ part2,
    const uint16_t* __restrict__ wp, const float* __restrict__ biasp,
    const float* __restrict__ ob, uint16_t* __restrict__ M2,
    float* __restrict__ bias2) {
  __shared__ float sctx[4224];
  __shared__ float sow[128];
  __shared__ float smrow[128];
  __shared__ float rb[4];
  const int o = blockIdx.x; const int t = threadIdx.x;
  for (int i = t; i < 4224; i += 256) {
    float s = 0.f;
    #pragma unroll
    for (int g = 0; g < 8; ++g) s += part2[g * 4224 + i];
    sctx[i] = s;
  }
  if (t < 128) sow[t] = ow[(size_t)o * 128 + t];
  __syncthreads();
  if (t < 128) {
    int h = t >> 5, d = t & 31;
    const float* cs = sctx + h * 1056;
    float den = cs[1024 + d];
    float s = 0.f;
    #pragma unroll
    for (int e = 0; e < 32; ++e) {
      int er = (e + d) & 31;             // rotated start: bank-conflict-free
      s += sow[h * 32 + er] * cs[d * 32 + er];
    }
    smrow[t] = s / den;
  }
  __syncthreads();
  float acc = 0.f;
  for (int d = 0; d < 128; ++d) acc += smrow[d] * b2f(wp[(size_t)d * 256 + t]);
  M2[(size_t)o * 256 + t] = f2b(acc);
  float p = (t < 128) ? smrow[t] * biasp[t] : 0.f;
  for (int m = 32; m >= 1; m >>= 1) p += __shfl_xor(p, m, 64);
  if ((t & 63) == 0) rb[t >> 6] = p;
  __syncthreads();
  if (t == 0) bias2[o] = ob[o] + rb[0] + rb[1] + rb[2] + rb[3];
}

// ---------------------------------------------------------------------------
// K7: out = M2(256x256 bf16) @ xT + bias2.  async16 staging; staged stores
// (nontemporal).  XCD-pairing swizzle.  grid 1024, block 256.
__global__ __launch_bounds__(256, 4) void k7_out(
    const uint16_t* __restrict__ xT, const uint16_t* __restrict__ M2,
    const float* __restrict__ bias2, float* __restrict__ out) {
  __shared__ __align__(16) char smem[32768];
  const int t = threadIdx.x;
  const int ltile = (blockIdx.x & 7) * 128 + (blockIdx.x >> 3);   // bijective, 1024%8==0
  const int mt = ltile & 1, nt = ltile >> 1;
  const int o0 = mt * 128, n0 = nt * 128;
  const int l = t & 63, wid = t >> 6, wr = wid >> 1, wc = wid & 1;
  const int lrow = l & 15, lk = l >> 4;

  f32x4 acc[4][4] = {};
  for (int ks = 0; ks < 4; ++ks) {
    const int k0 = ks * 64;
    __syncthreads();
    #pragma unroll
    for (int it = 0; it < 4; ++it) {
      int s = it * 256 + t;
      int row = s >> 3, c = s & 7;
      const char* gsrc = (const char*)M2 + (size_t)(o0 + row) * 512 + k0 * 2 + ((c ^ (row & 7)) << 4);
      async16(gsrc, smem + (s & ~63) * 16);
    }
    #pragma unroll
    for (int it = 0; it < 4; ++it) {
      int s = it * 256 + t;
      int row = s >> 3, c = s & 7;
      const char* gsrc = (const char*)xT + (size_t)(n0 + row) * 512 + k0 * 2 + ((c ^ (row & 7)) << 4);
      async16(gsrc, smem + 16384 + (s & ~63) * 16);
    }
    __syncthreads();
    #pragma unroll
    for (int kk = 0; kk < 2; ++kk) {
      short8 a[4], b[4];
      #pragma unroll
      for (int m = 0; m < 4; ++m) {
        int row = wr * 64 + m * 16 + lrow;
        a[m] = *(const short8*)(&smem[row * 128 + (((kk * 4 + lk) ^ (row & 7)) << 4)]);
      }
      #pragma unroll
      for (int n = 0; n < 4; ++n) {
        int row = wc * 64 + n * 16 + lrow;
        b[n] = *(const short8*)(&smem[16384 + row * 128 + (((kk * 4 + lk) ^ (row & 7)) << 4)]);
      }
      #pragma unroll
      for (int m = 0; m < 4; ++m)
        #pragma unroll
        for (int n = 0; n < 4; ++n)
          acc[m][n] = __builtin_amdgcn_mfma_f32_16x16x32_bf16(a[m], b[n], acc[m][n], 0, 0, 0);
    }
  }

  #pragma unroll
  for (int half = 0; half < 2; ++half) {
    __syncthreads();
    if (wr == half) {
      #pragma unroll
      for (int m = 0; m < 4; ++m) {
        int rb = m * 16 + lk * 4;
        float bb[4];
        #pragma unroll
        for (int j = 0; j < 4; ++j) bb[j] = bias2[o0 + half * 64 + rb + j];
        #pragma unroll
        for (int n = 0; n < 4; ++n) {
          int col = wc * 64 + n * 16 + lrow;
          #pragma unroll
          for (int j = 0; j < 4; ++j) {
            int row = rb + j;
            *(float*)(&smem[row * 512 + ((((col >> 2) ^ (row & 7)) << 4)) + (col & 3) * 4]) =
                acc[m][n][j] + bb[j];
          }
        }
      }
    }
    __syncthreads();
    #pragma unroll
    for (int p = 0; p < 8; ++p) {
      int flat = t + 256 * p; int row = flat >> 5, c = flat & 31;
      f32x4 v = *(const f32x4*)(&smem[row * 512 + (((c ^ (row & 7)) << 4))]);
      __builtin_nontemporal_store(
          v, (f32x4*)(out + (size_t)(o0 + half * 64 + row) * N_SPATIAL + n0 + c * 4));
    }
  }
}

// ---------------------------------------------------------------------------
extern "C" void kernel_launch(void* const* d_in, const int* in_sizes, int n_in,
                              void* d_out, int out_size, void* d_ws, size_t ws_size,
                              hipStream_t stream) {
  const float* x   = (const float*)d_in[0];
  const float* gnw = (const float*)d_in[1];
  const float* gnb = (const float*)d_in[2];
  const float* qw  = (const float*)d_in[3];
  const float* qb  = (const float*)d_in[4];
  const float* ow  = (const float*)d_in[5];
  const float* ob  = (const float*)d_in[6];
  float* out = (float*)d_out;
  char* ws = (char*)d_ws;

  uint16_t* xT    = (uint16_t*)(ws + 0);          // 32 MB
  uint16_t* wp    = (uint16_t*)(ws + 33554432);   // 192 KB
  float*    biasp = (float*)   (ws + 33751040);   // 1.5 KB
  float*    ab    = (float*)   (ws + 33753088);   // 2 KB
  float*    gnp   = (float*)   (ws + 33755136);   // 256 KB
  uint16_t* part  = (uint16_t*)(ws + 34017280);   // 8.65 MB (512*8448*2)
  float*    part2 = (float*)   (ws + 42668032);   // 132 KB (8*4224*4)
  uint16_t* M2    = (uint16_t*)(ws + 42803200);   // 128 KB
  float*    bias2 = (float*)   (ws + 42934272);   // 1 KB

  k1_transpose_stats<<<dim3(1024), dim3(256), 0, stream>>>(x, xT, gnp);
  k2_stats_final<<<dim3(32), dim3(256), 0, stream>>>(gnp, gnw, gnb, ab);
  k2b_fold_w<<<dim3(384), dim3(64), 0, stream>>>(qw, qb, ab, wp, biasp);
  k3_kv<<<dim3(512), dim3(512), 0, stream>>>(xT, wp, biasp, part);
  k6_reduce<<<dim3(136), dim3(256), 0, stream>>>(part, part2);
  kM_fold<<<dim3(256), dim3(256), 0, stream>>>(ow, part2, wp, biasp, ob, M2, bias2);
  k7_out<<<dim3(1024), dim3(256), 0, stream>>>(xT, M2, bias2, out);
}

// Round 16
// 81.748 us; speedup vs baseline: 1.0714x; 1.0714x over previous
//
#include <hip/hip_runtime.h>
#include <stdint.h>

typedef float f32x4 __attribute__((ext_vector_type(4)));
typedef short short8 __attribute__((ext_vector_type(8)));
typedef short short4v __attribute__((ext_vector_type(4)));

#define N_SPATIAL 65536   // 256*256

__device__ __forceinline__ float b2f(uint16_t u) {
  union { uint32_t u; float f; } v; v.u = ((uint32_t)u) << 16; return v.f;
}
__device__ __forceinline__ uint16_t f2b(float f) {
  union { float f; uint32_t u; } v; v.f = f;
  uint32_t r = (v.u + 0x7FFFu + ((v.u >> 16) & 1u)) >> 16;
  return (uint16_t)r;
}

// async 16B global -> LDS (direct).  LDS dest wave-uniform base + lane*16.
__device__ __forceinline__ void async16(const void* g, void* l) {
  __builtin_amdgcn_global_load_lds(
      (__attribute__((address_space(1))) void*)g,
      (__attribute__((address_space(3))) void*)l, 16, 0, 0);
}

// ---------------------------------------------------------------------------
// K1 (R10-proven): transpose x (c,n) fp32 -> xT (n,c) bf16 + GN partial stats.
// grid 1024 (64-n tiles), block 256.
__global__ __launch_bounds__(256) void k1_transpose_stats(
    const float* __restrict__ x, uint16_t* __restrict__ xT, float* __restrict__ gnp) {
  __shared__ uint16_t xs[64][264];   // [n][c] padded stride 264
  const int t = threadIdx.x;
  const int n0 = blockIdx.x * 64;
  const int c_l = (t >> 2) & 15;
  const int nq  = (t & 3) + 4 * (t >> 6);
  for (int p = 0; p < 16; ++p) {
    int c = 16 * p + c_l;
    float4 v = *(const float4*)(x + (size_t)c * N_SPATIAL + n0 + nq * 4);
    int nn = nq * 4;
    xs[nn + 0][c] = f2b(v.x); xs[nn + 1][c] = f2b(v.y);
    xs[nn + 2][c] = f2b(v.z); xs[nn + 3][c] = f2b(v.w);
  }
  __syncthreads();
  {
    int g = t >> 3; int c = g * 8 + (t & 7);
    float s = 0.f, ss = 0.f;
    for (int n = 0; n < 64; ++n) { float f = b2f(xs[n][c]); s += f; ss += f * f; }
    s  += __shfl_xor(s, 1, 64);  ss += __shfl_xor(ss, 1, 64);
    s  += __shfl_xor(s, 2, 64);  ss += __shfl_xor(ss, 2, 64);
    s  += __shfl_xor(s, 4, 64);  ss += __shfl_xor(ss, 4, 64);
    if ((t & 7) == 0) {
      gnp[((size_t)blockIdx.x * 32 + g) * 2 + 0] = s;
      gnp[((size_t)blockIdx.x * 32 + g) * 2 + 1] = ss;
    }
  }
  for (int p = 0; p < 8; ++p) {
    int j = t + 256 * p; int n = j >> 5; int c16 = j & 31;
    f32x4 val = *(const f32x4*)((const char*)&xs[0][0] + n * 528 + c16 * 16);
    *(f32x4*)((char*)xT + ((size_t)(n0 + n)) * 512 + c16 * 16) = val;
  }
}

// ---------------------------------------------------------------------------
// K2s: reduce stats partials -> per-channel a,b.  grid 32, block 256.
__global__ __launch_bounds__(256) void k2_stats_final(
    const float* __restrict__ gnp, const float* __restrict__ gnw,
    const float* __restrict__ gnb, float* __restrict__ ab) {
  __shared__ float red[4][2];
  const int g = blockIdx.x; const int t = threadIdx.x;
  float s = 0.f, ss = 0.f;
  for (int c = t; c < 1024; c += 256) {
    s  += gnp[((size_t)c * 32 + g) * 2 + 0];
    ss += gnp[((size_t)c * 32 + g) * 2 + 1];
  }
  for (int m = 32; m >= 1; m >>= 1) { s += __shfl_xor(s, m, 64); ss += __shfl_xor(ss, m, 64); }
  if ((t & 63) == 0) { red[t >> 6][0] = s; red[t >> 6][1] = ss; }
  __syncthreads();
  if (t == 0) {
    float S  = red[0][0] + red[1][0] + red[2][0] + red[3][0];
    float SS = red[0][1] + red[1][1] + red[2][1] + red[3][1];
    const float invN = 1.0f / 524288.0f;
    float mean = S * invN;
    float var  = SS * invN - mean * mean;
    float rs   = rsqrtf(var + 1e-5f);
    for (int i = 0; i < 8; ++i) {
      int c = g * 8 + i;
      float aa = gnw[c] * rs;
      ab[c] = aa;
      ab[256 + c] = gnb[c] - mean * aa;
    }
  }
}

// ---------------------------------------------------------------------------
// K2w: fold norm into qkv weights.  grid 384, block 64.
__global__ __launch_bounds__(64) void k2b_fold_w(
    const float* __restrict__ qw, const float* __restrict__ qb,
    const float* __restrict__ ab, uint16_t* __restrict__ wp, float* __restrict__ biasp) {
  const int o = blockIdx.x; const int l = threadIdx.x;
  float4 w  = *(const float4*)(qw + (size_t)o * 256 + l * 4);
  float4 av = *(const float4*)(ab + l * 4);
  float4 bv = *(const float4*)(ab + 256 + l * 4);
  short4v pk;
  pk[0] = (short)f2b(w.x * av.x); pk[1] = (short)f2b(w.y * av.y);
  pk[2] = (short)f2b(w.z * av.z); pk[3] = (short)f2b(w.w * av.w);
  *(short4v*)(wp + (size_t)o * 256 + l * 4) = pk;
  float part = w.x * bv.x + w.y * bv.y + w.z * bv.z + w.w * bv.w;
  for (int m = 32; m >= 1; m >>= 1) part += __shfl_xor(part, m, 64);
  if (l == 0) biasp[o] = qb[o] + part;
}

// ---------------------------------------------------------------------------
// K3kv (R13-proven): k,v GEMM (async16 staging) + in-block context.
// grid 1024 (64 px each), block 256, 4 blocks/CU.  bf16 partials.
__global__ __launch_bounds__(256, 4) void k3_kv(
    const uint16_t* __restrict__ xT, const uint16_t* __restrict__ wp,
    const float* __restrict__ biasp, uint16_t* __restrict__ part) {
  __shared__ __align__(16) char smem[40960]; // A[0,32K) B[32K,40K); ek[0,16K) v[16K,32K) reuse
  const int t = threadIdx.x;
  const int l = t & 63, wid = t >> 6;
  const int lrow = l & 15, lk = l >> 4;

  const int n0 = blockIdx.x * 64;
  f32x4 acc[4][4] = {};
  for (int ks = 0; ks < 4; ++ks) {
    const int k0 = ks * 64;
    __syncthreads();
    #pragma unroll
    for (int it = 0; it < 8; ++it) {
      int s = it * 256 + t;
      int row = s >> 3, c = s & 7;
      const char* gsrc = (const char*)wp + (size_t)(128 + row) * 512 + k0 * 2 + ((c ^ (row & 7)) << 4);
      async16(gsrc, smem + (s & ~63) * 16);
    }
    #pragma unroll
    for (int it = 0; it < 2; ++it) {
      int s = it * 256 + t;
      int row = s >> 3, c = s & 7;
      const char* gsrc = (const char*)xT + (size_t)(n0 + row) * 512 + k0 * 2 + ((c ^ (row & 7)) << 4);
      async16(gsrc, smem + 32768 + (s & ~63) * 16);
    }
    __syncthreads();
    #pragma unroll
    for (int kk = 0; kk < 2; ++kk) {
      short8 a[4], b[4];
      #pragma unroll
      for (int m = 0; m < 4; ++m) {
        int row = wid * 64 + m * 16 + lrow;
        a[m] = *(const short8*)(&smem[row * 128 + (((kk * 4 + lk) ^ (row & 7)) << 4)]);
      }
      #pragma unroll
      for (int n = 0; n < 4; ++n) {
        int row = n * 16 + lrow;
        b[n] = *(const short8*)(&smem[32768 + row * 128 + (((kk * 4 + lk) ^ (row & 7)) << 4)]);
      }
      #pragma unroll
      for (int m = 0; m < 4; ++m)
        #pragma unroll
        for (int n = 0; n < 4; ++n)
          acc[m][n] = __builtin_amdgcn_mfma_f32_16x16x32_bf16(a[m], b[n], acc[m][n], 0, 0, 0);
    }
  }
  __syncthreads();

  float denp[16];
  #pragma unroll
  for (int i = 0; i < 16; ++i) denp[i] = 0.f;
  {
    const bool isk = wid < 2;
    const int base = isk ? 0 : 16384;
    #pragma unroll
    for (int m = 0; m < 4; ++m) {
      float bb[4];
      #pragma unroll
      for (int j = 0; j < 4; ++j) bb[j] = biasp[128 + wid * 64 + m * 16 + lk * 4 + j];
      #pragma unroll
      for (int n = 0; n < 4; ++n) {
        int col = n * 16 + lrow;
        int coff = col >> 3, cbyte = (col & 7) * 2;
        #pragma unroll
        for (int j = 0; j < 4; ++j) {
          int rloc = ((wid * 64) & 127) + m * 16 + lk * 4 + j;   // row within 128
          float val = acc[m][n][j] + bb[j];
          if (isk) { val = __expf(val); denp[m * 4 + j] += val; }
          *(uint16_t*)(&smem[base + rloc * 128 + ((coff ^ (rloc & 7)) << 4) + cbyte]) = f2b(val);
        }
      }
    }
  }
  __syncthreads();

  f32x4 cacc[2][2] = {};
  {
    const int h = wid;
    #pragma unroll
    for (int kw = 0; kw < 2; ++kw) {
      short8 ae[2], be[2];
      #pragma unroll
      for (int mf = 0; mf < 2; ++mf) {
        int row = h * 32 + mf * 16 + lrow;
        ae[mf] = *(const short8*)(&smem[row * 128 + (((kw * 4 + lk) ^ (row & 7)) << 4)]);
      }
      #pragma unroll
      for (int nf = 0; nf < 2; ++nf) {
        int row = h * 32 + nf * 16 + lrow;
        be[nf] = *(const short8*)(&smem[16384 + row * 128 + (((kw * 4 + lk) ^ (row & 7)) << 4)]);
      }
      #pragma unroll
      for (int mf = 0; mf < 2; ++mf)
        #pragma unroll
        for (int nf = 0; nf < 2; ++nf)
          cacc[mf][nf] = __builtin_amdgcn_mfma_f32_16x16x32_bf16(ae[mf], be[nf], cacc[mf][nf], 0, 0, 0);
    }
  }
  uint16_t* pp = part + (size_t)blockIdx.x * 4224;
  {
    uint16_t* ph = pp + wid * 1056;
    #pragma unroll
    for (int mf = 0; mf < 2; ++mf)
      #pragma unroll
      for (int nf = 0; nf < 2; ++nf)
        #pragma unroll
        for (int j = 0; j < 4; ++j) {
          int d = mf * 16 + lk * 4 + j, e = nf * 16 + lrow;
          ph[d * 32 + e] = f2b(cacc[mf][nf][j]);
        }
  }
  if (wid < 2) {
    #pragma unroll
    for (int i = 0; i < 16; ++i) {
      denp[i] += __shfl_xor(denp[i], 1, 64);
      denp[i] += __shfl_xor(denp[i], 2, 64);
      denp[i] += __shfl_xor(denp[i], 4, 64);
      denp[i] += __shfl_xor(denp[i], 8, 64);
    }
    if (lrow == 0) {
      #pragma unroll
      for (int m = 0; m < 4; ++m)
        #pragma unroll
        for (int j = 0; j < 4; ++j) {
          int r = wid * 64 + m * 16 + lk * 4 + j;   // 0..127 k-row
          pp[(r >> 5) * 1056 + 1024 + (r & 31)] = f2b(denp[m * 4 + j]);
        }
    }
  }
}

// ---------------------------------------------------------------------------
// K6 (R10-proven 8-way): reduce bf16 partials over 1024 blocks.
// grid 136 = 17 x 8.  part2[8][4224] fp32.
__global__ __launch_bounds__(256) void k6_reduce(
    const uint16_t* __restrict__ part, float* __restrict__ part2) {
  const int bx = blockIdx.x;
  const int idb = bx % 17, cg = bx / 17;
  const int id = idb * 256 + threadIdx.x;
  if (id >= 4224) return;
  const uint16_t* p = part + (size_t)cg * 128 * 4224 + id;
  float s0 = 0.f, s1 = 0.f, s2 = 0.f, s3 = 0.f;
  for (int c = 0; c < 128; c += 4) {
    s0 += b2f(p[(size_t)(c + 0) * 4224]);
    s1 += b2f(p[(size_t)(c + 1) * 4224]);
    s2 += b2f(p[(size_t)(c + 2) * 4224]);
    s3 += b2f(p[(size_t)(c + 3) * 4224]);
  }
  part2[cg * 4224 + id] = (s0 + s1) + (s2 + s3);
}

// ---------------------------------------------------------------------------
// KM (R10-proven): merged M-fold + M2-fold (sums the 8 part2 chunks on load).
// grid 256, block 256.
__global__ __launch_bounds__(256) void kM_fold(
    const float* __restrict__ ow, const float* __restrict__ part2,
    const uint16_t* __restrict__ wp, const float* __restrict__ biasp,
    const float* __restrict__ ob, uint16_t* __restrict__ M2,
    float* __restrict__ bias2) {
  __shared__ float sctx[4224];
  __shared__ float sow[128];
  __shared__ float smrow[128];
  __shared__ float rb[4];
  const int o = blockIdx.x; const int t = threadIdx.x;
  for (int i = t; i < 4224; i += 256) {
    float s = 0.f;
    #pragma unroll
    for (int g = 0; g < 8; ++g) s += part2[g * 4224 + i];
    sctx[i] = s;
  }
  if (t < 128) sow[t] = ow[(size_t)o * 128 + t];
  __syncthreads();
  if (t < 128) {
    int h = t >> 5, d = t & 31;
    const float* cs = sctx + h * 1056;
    float den = cs[1024 + d];
    float s = 0.f;
    #pragma unroll
    for (int e = 0; e < 32; ++e) {
      int er = (e + d) & 31;             // rotated start: bank-conflict-free
      s += sow[h * 32 + er] * cs[d * 32 + er];
    }
    smrow[t] = s / den;
  }
  __syncthreads();
  float acc = 0.f;
  for (int d = 0; d < 128; ++d) acc += smrow[d] * b2f(wp[(size_t)d * 256 + t]);
  M2[(size_t)o * 256 + t] = f2b(acc);
  float p = (t < 128) ? smrow[t] * biasp[t] : 0.f;
  for (int m = 32; m >= 1; m >>= 1) p += __shfl_xor(p, m, 64);
  if ((t & 63) == 0) rb[t >> 6] = p;
  __syncthreads();
  if (t == 0) bias2[o] = ob[o] + rb[0] + rb[1] + rb[2] + rb[3];
}

// ---------------------------------------------------------------------------
// K7 (R13-proven): out = M2(256x256 bf16) @ xT + bias2.  async16 staging;
// staged coalesced stores; XCD-pairing swizzle.  grid 1024, block 256.
__global__ __launch_bounds__(256, 4) void k7_out(
    const uint16_t* __restrict__ xT, const uint16_t* __restrict__ M2,
    const float* __restrict__ bias2, float* __restrict__ out) {
  __shared__ __align__(16) char smem[32768];
  const int t = threadIdx.x;
  const int ltile = (blockIdx.x & 7) * 128 + (blockIdx.x >> 3);   // bijective, 1024%8==0
  const int mt = ltile & 1, nt = ltile >> 1;
  const int o0 = mt * 128, n0 = nt * 128;
  const int l = t & 63, wid = t >> 6, wr = wid >> 1, wc = wid & 1;
  const int lrow = l & 15, lk = l >> 4;

  f32x4 acc[4][4] = {};
  for (int ks = 0; ks < 4; ++ks) {
    const int k0 = ks * 64;
    __syncthreads();
    #pragma unroll
    for (int it = 0; it < 4; ++it) {
      int s = it * 256 + t;
      int row = s >> 3, c = s & 7;
      const char* gsrc = (const char*)M2 + (size_t)(o0 + row) * 512 + k0 * 2 + ((c ^ (row & 7)) << 4);
      async16(gsrc, smem + (s & ~63) * 16);
    }
    #pragma unroll
    for (int it = 0; it < 4; ++it) {
      int s = it * 256 + t;
      int row = s >> 3, c = s & 7;
      const char* gsrc = (const char*)xT + (size_t)(n0 + row) * 512 + k0 * 2 + ((c ^ (row & 7)) << 4);
      async16(gsrc, smem + 16384 + (s & ~63) * 16);
    }
    __syncthreads();
    #pragma unroll
    for (int kk = 0; kk < 2; ++kk) {
      short8 a[4], b[4];
      #pragma unroll
      for (int m = 0; m < 4; ++m) {
        int row = wr * 64 + m * 16 + lrow;
        a[m] = *(const short8*)(&smem[row * 128 + (((kk * 4 + lk) ^ (row & 7)) << 4)]);
      }
      #pragma unroll
      for (int n = 0; n < 4; ++n) {
        int row = wc * 64 + n * 16 + lrow;
        b[n] = *(const short8*)(&smem[16384 + row * 128 + (((kk * 4 + lk) ^ (row & 7)) << 4)]);
      }
      #pragma unroll
      for (int m = 0; m < 4; ++m)
        #pragma unroll
        for (int n = 0; n < 4; ++n)
          acc[m][n] = __builtin_amdgcn_mfma_f32_16x16x32_bf16(a[m], b[n], acc[m][n], 0, 0, 0);
    }
  }

  #pragma unroll
  for (int half = 0; half < 2; ++half) {
    __syncthreads();
    if (wr == half) {
      #pragma unroll
      for (int m = 0; m < 4; ++m) {
        int rb = m * 16 + lk * 4;
        float bb[4];
        #pragma unroll
        for (int j = 0; j < 4; ++j) bb[j] = bias2[o0 + half * 64 + rb + j];
        #pragma unroll
        for (int n = 0; n < 4; ++n) {
          int col = wc * 64 + n * 16 + lrow;
          #pragma unroll
          for (int j = 0; j < 4; ++j) {
            int row = rb + j;
            *(float*)(&smem[row * 512 + ((((col >> 2) ^ (row & 7)) << 4)) + (col & 3) * 4]) =
                acc[m][n][j] + bb[j];
          }
        }
      }
    }
    __syncthreads();
    #pragma unroll
    for (int p = 0; p < 8; ++p) {
      int flat = t + 256 * p; int row = flat >> 5, c = flat & 31;
      f32x4 v = *(const f32x4*)(&smem[row * 512 + (((c ^ (row & 7)) << 4))]);
      *(f32x4*)(out + (size_t)(o0 + half * 64 + row) * N_SPATIAL + n0 + c * 4) = v;
    }
  }
}

// ---------------------------------------------------------------------------
extern "C" void kernel_launch(void* const* d_in, const int* in_sizes, int n_in,
                              void* d_out, int out_size, void* d_ws, size_t ws_size,
                              hipStream_t stream) {
  const float* x   = (const float*)d_in[0];
  const float* gnw = (const float*)d_in[1];
  const float* gnb = (const float*)d_in[2];
  const float* qw  = (const float*)d_in[3];
  const float* qb  = (const float*)d_in[4];
  const float* ow  = (const float*)d_in[5];
  const float* ob  = (const float*)d_in[6];
  float* out = (float*)d_out;
  char* ws = (char*)d_ws;

  uint16_t* xT    = (uint16_t*)(ws + 0);          // 32 MB
  uint16_t* wp    = (uint16_t*)(ws + 33554432);   // 192 KB
  float*    biasp = (float*)   (ws + 33751040);   // 1.5 KB
  float*    ab    = (float*)   (ws + 33753088);   // 2 KB
  float*    gnp   = (float*)   (ws + 33755136);   // 256 KB
  uint16_t* part  = (uint16_t*)(ws + 34017280);   // 8.65 MB (1024*4224*2)
  float*    part2 = (float*)   (ws + 42668032);   // 132 KB (8*4224*4)
  uint16_t* M2    = (uint16_t*)(ws + 42803200);   // 128 KB
  float*    bias2 = (float*)   (ws + 42934272);   // 1 KB

  k1_transpose_stats<<<dim3(1024), dim3(256), 0, stream>>>(x, xT, gnp);
  k2_stats_final<<<dim3(32), dim3(256), 0, stream>>>(gnp, gnw, gnb, ab);
  k2b_fold_w<<<dim3(384), dim3(64), 0, stream>>>(qw, qb, ab, wp, biasp);
  k3_kv<<<dim3(1024), dim3(256), 0, stream>>>(xT, wp, biasp, part);
  k6_reduce<<<dim3(136), dim3(256), 0, stream>>>(part, part2);
  kM_fold<<<dim3(256), dim3(256), 0, stream>>>(ow, part2, wp, biasp, ob, M2, bias2);
  k7_out<<<dim3(1024), dim3(256), 0, stream>>>(xT, M2, bias2, out);
}